// Round 2
// baseline (289.821 us; speedup 1.0000x reference)
//
#include <hip/hip_runtime.h>

#define N_B   262144
#define BM    64       // 64 rows/block -> LDS 37.4 KB -> 4 blocks/CU (was 2)
#define KAUG  288      // 256 (h) + 32 (x-augmentation, only 3 used)
#define LDA   264      // hA row stride in halves: 528B = 33*16B; 132 dw = 4 mod 32 -> 2-way bank alias (free)

typedef _Float16 f16x8 __attribute__((ext_vector_type(8)));
typedef _Float16 f16x4 __attribute__((ext_vector_type(4)));
typedef float    f32x4 __attribute__((ext_vector_type(4)));

// ---------------------------------------------------------------------------
// Precompute (68 blocks, ~5 us):
//   blocks 0..63 : (l = b>>4, row-group ng = b&15) -> Mt[l][16ng..16ng+16)[*]
//   blocks 64..67: W1t[n][k] = W1[k][n] transpose.
// ---------------------------------------------------------------------------
__global__ void fno_precompute(const float* __restrict__ W1,
                               const float* __restrict__ fw,
                               const float* __restrict__ lw,
                               _Float16* __restrict__ Mt,    // [4][256][KAUG]
                               _Float16* __restrict__ W1t)   // [256][64]
{
    const int t = threadIdx.x;          // 0..255
    const int b = blockIdx.x;
    if (b < 64) {
        const int l  = b >> 4;
        const int ng = b & 15;
        __shared__ float cosTab[256];
        __shared__ float cs[256];
        cosTab[t] = cosf((float)t * (6.28318530717958647692f / 256.0f));
        __syncthreads();
        // cs[t] = irfft(fw_l)[t]
        {
            const float* fwl = fw + l * 129;
            float s = fwl[0];
            #pragma unroll 4
            for (int k = 1; k < 128; ++k)
                s += 2.0f * fwl[k] * cosTab[(k * t) & 255];
            s += fwl[128] * ((t & 1) ? -1.0f : 1.0f);
            cs[t] = s * (1.0f / 256.0f);
        }
        __syncthreads();
        for (int idx = t; idx < 16 * KAUG; idx += 256) {
            const int n = ng * 16 + idx / KAUG;
            const int k = idx % KAUG;
            float v = 0.0f;
            if (k < 253)               v = cs[(n - k - 3) & 255];  // conv: h[k] -> d[k+3]
            if (k == n)                v += lw[l * 256 + n];       // diagonal residual lw
            if (k >= 256 && k < 259)   v = cs[(n - (k - 256)) & 255]; // x rows
            Mt[((size_t)l * 256 + n) * KAUG + k] = (_Float16)v;
        }
    } else {
        const int base = (b - 64) * 4096;
        #pragma unroll
        for (int i = 0; i < 16; ++i) {
            const int idx = base + t + i * 256;
            const int n = idx >> 6, k = idx & 63;
            W1t[idx] = (_Float16)W1[k * 256 + n];
        }
    }
}

// ---------------------------------------------------------------------------
// Fused main kernel. Block = 64 rows x 256 threads (4 waves); wave w owns
// feature columns [64w, 64w+64). 4 blocks/CU (LDS 37.4 KB).
// x-augmentation lives in hA cols 256..258 (LDA pad); the ks=8 K-chunk reads
// cols 256..287: cols 259..263 are zeros, cols 264..287 over-read into the
// next row's h values -- finite, and multiplied by exactly-zero Mt weights.
// Pad row BM is zeroed so the last row's over-read never sees uninit LDS
// (NaN * 0 = NaN would poison the accumulator).
// MFMA operand order is (Mt_frag, h_frag) so D = h^T-layout: lane holds
// row = lane&15, features 4q..4q+3 -> vectorized f16x4 epilogue writes.
// ---------------------------------------------------------------------------
__global__ __launch_bounds__(256, 4)
void fno_main(const float* __restrict__ mu,
              const float* __restrict__ x,
              const float* __restrict__ b1,
              const float* __restrict__ W2,
              const float* __restrict__ b2,
              const _Float16* __restrict__ Mt,
              const _Float16* __restrict__ W1t,
              float* __restrict__ out)
{
    __shared__ __align__(16) _Float16 hA[(BM + 1) * LDA];  // h state + x cols + pad row
    __shared__ float b1s[256];
    __shared__ float W2s[256];
    __shared__ float red[256];

    const int t    = threadIdx.x;
    const int w    = t >> 6;        // wave id: feature stripe 64*w
    const int lane = t & 63;
    const int i16  = lane & 15;     // Mt-frag feature / h-frag row / D row
    const int q    = lane >> 4;     // quad: k-chunk (inputs), feature group (D)
    const int r0   = blockIdx.x * BM;

    // ---- stage mu -> hA cols 0..63 (fp16); x -> cols 256..263; zero pad row ----
    {
        const float4* mu4 = (const float4*)mu + (size_t)r0 * 16;  // 16 float4 per row
        #pragma unroll
        for (int j = 0; j < 4; ++j) {
            int f = t + 256 * j;
            int row = f >> 4, c4 = f & 15;
            float4 v = mu4[f];
            f16x4 h;
            h[0] = (_Float16)v.x; h[1] = (_Float16)v.y;
            h[2] = (_Float16)v.z; h[3] = (_Float16)v.w;
            *(f16x4*)&hA[row * LDA + c4 * 4] = h;
        }
        if (t < BM) {
            const float* xp = x + (size_t)(r0 + t) * 3;
            f16x8 hx = {(_Float16)xp[0], (_Float16)xp[1], (_Float16)xp[2],
                        (_Float16)0, (_Float16)0, (_Float16)0,
                        (_Float16)0, (_Float16)0};
            *(f16x8*)&hA[t * LDA + 256] = hx;
        }
        if (t < 33) {              // 33 * 8 = 264 halves: the whole pad row
            f16x8 z8 = {};
            *(f16x8*)&hA[BM * LDA + 8 * t] = z8;
        }
        b1s[t] = b1[t];
        W2s[t] = W2[t];
    }
    __syncthreads();

    const f32x4 fz = {0.f, 0.f, 0.f, 0.f};
    f32x4 acc[4][4];   // [feature-tile][row-tile], 64 regs

    // ================= encoder: h = relu(mu @ W1 + b1), K = 64 =================
    #pragma unroll
    for (int ft = 0; ft < 4; ++ft)
        #pragma unroll
        for (int rt = 0; rt < 4; ++rt) acc[ft][rt] = fz;

    #pragma unroll
    for (int ks = 0; ks < 2; ++ks) {
        const int kb = ks * 32;
        f16x8 mfrag[4];
        #pragma unroll
        for (int ft = 0; ft < 4; ++ft) {
            int n = 64 * w + 16 * ft + i16;
            mfrag[ft] = *(const f16x8*)(W1t + n * 64 + kb + 8 * q);
        }
        #pragma unroll
        for (int rt = 0; rt < 4; ++rt) {
            f16x8 hfrag = *(const f16x8*)&hA[(16 * rt + i16) * LDA + kb + 8 * q];
            #pragma unroll
            for (int ft = 0; ft < 4; ++ft)
                acc[ft][rt] = __builtin_amdgcn_mfma_f32_16x16x32_f16(
                    mfrag[ft], hfrag, acc[ft][rt], 0, 0, 0);
        }
    }
    __syncthreads();   // all reads of mu-region done before overwrite
    #pragma unroll
    for (int ft = 0; ft < 4; ++ft) {
        const int f = 64 * w + 16 * ft + 4 * q;
        const float4 bias = *(const float4*)&b1s[f];
        #pragma unroll
        for (int rt = 0; rt < 4; ++rt) {
            const int row = 16 * rt + i16;
            f32x4 v = acc[ft][rt];
            f16x4 hv;
            hv[0] = (_Float16)fmaxf(v[0] + bias.x, 0.f);
            hv[1] = (_Float16)fmaxf(v[1] + bias.y, 0.f);
            hv[2] = (_Float16)fmaxf(v[2] + bias.z, 0.f);
            hv[3] = (_Float16)fmaxf(v[3] + bias.w, 0.f);
            *(f16x4*)&hA[row * LDA + f] = hv;
        }
    }

    // ================= 4 Fourier layers: h = relu([h|x] @ M_l) ================
    #pragma unroll 1
    for (int l = 0; l < 4; ++l) {
        __syncthreads();   // hA writes from previous stage visible
        #pragma unroll
        for (int ft = 0; ft < 4; ++ft)
            #pragma unroll
            for (int rt = 0; rt < 4; ++rt) acc[ft][rt] = fz;

        const _Float16* Ml = Mt + (size_t)l * 256 * KAUG;
        #pragma unroll
        for (int ks = 0; ks < 9; ++ks) {
            const int kb = ks * 32;
            f16x8 mfrag[4];
            #pragma unroll
            for (int ft = 0; ft < 4; ++ft) {
                int n = 64 * w + 16 * ft + i16;
                mfrag[ft] = *(const f16x8*)(Ml + n * KAUG + kb + 8 * q);
            }
            #pragma unroll
            for (int rt = 0; rt < 4; ++rt) {
                // ks==8 reads cols 256..287: x cols + zeros + next-row overlap (zero weights)
                f16x8 hfrag = *(const f16x8*)&hA[(16 * rt + i16) * LDA + kb + 8 * q];
                #pragma unroll
                for (int ft = 0; ft < 4; ++ft)
                    acc[ft][rt] = __builtin_amdgcn_mfma_f32_16x16x32_f16(
                        mfrag[ft], hfrag, acc[ft][rt], 0, 0, 0);
            }
        }
        __syncthreads();   // all hA reads done before overwrite
        #pragma unroll
        for (int ft = 0; ft < 4; ++ft) {
            const int f = 64 * w + 16 * ft + 4 * q;
            #pragma unroll
            for (int rt = 0; rt < 4; ++rt) {
                const int row = 16 * rt + i16;
                f32x4 v = acc[ft][rt];
                f16x4 hv;
                hv[0] = (_Float16)fmaxf(v[0], 0.f);
                hv[1] = (_Float16)fmaxf(v[1], 0.f);
                hv[2] = (_Float16)fmaxf(v[2], 0.f);
                hv[3] = (_Float16)fmaxf(v[3], 0.f);
                *(f16x4*)&hA[row * LDA + f] = hv;
            }
        }
    }

    // ================= decoder: out = h @ W2 + b2 =============================
    __syncthreads();
    {
        const int r  = t & 63;          // row (lane)
        const int n0 = w * 64;          // wave w covers cols 64w..64w+63
        float s = 0.f;
        #pragma unroll
        for (int j = 0; j < 8; ++j) {
            f16x8 v = *(const f16x8*)&hA[r * LDA + n0 + 8 * j];
            const float* wp = &W2s[n0 + 8 * j];
            s += (float)v[0] * wp[0] + (float)v[1] * wp[1]
               + (float)v[2] * wp[2] + (float)v[3] * wp[3]
               + (float)v[4] * wp[4] + (float)v[5] * wp[5]
               + (float)v[6] * wp[6] + (float)v[7] * wp[7];
        }
        red[t] = s;
        __syncthreads();
        if (t < 64)
            out[r0 + t] = red[t] + red[64 + t] + red[128 + t] + red[192 + t] + b2[0];
    }
}

// ---------------------------------------------------------------------------
extern "C" void kernel_launch(void* const* d_in, const int* in_sizes, int n_in,
                              void* d_out, int out_size, void* d_ws, size_t ws_size,
                              hipStream_t stream) {
    const float* mu = (const float*)d_in[0];
    const float* x  = (const float*)d_in[1];
    const float* W1 = (const float*)d_in[2];
    const float* b1 = (const float*)d_in[3];
    const float* fw = (const float*)d_in[4];
    const float* lw = (const float*)d_in[5];
    const float* W2 = (const float*)d_in[6];
    const float* b2 = (const float*)d_in[7];
    float* out = (float*)d_out;

    _Float16* Mt  = (_Float16*)d_ws;
    _Float16* W1t = Mt + 4 * 256 * KAUG;

    fno_precompute<<<68, 256, 0, stream>>>(W1, fw, lw, Mt, W1t);
    fno_main<<<N_B / BM, 256, 0, stream>>>(mu, x, b1, W2, b2, Mt, W1t, out);
}

// Round 3
// 284.247 us; speedup vs baseline: 1.0196x; 1.0196x over previous
//
#include <hip/hip_runtime.h>

#define N_B   262144
#define BM    64       // 64 rows/block -> LDS 37.4 KB
#define KAUG  288      // 256 (h) + 32 (x-augmentation, only 3 used)
#define LDA   264      // hA row stride in halves: 528B; 132 dw = 4 mod 32 -> 2-way bank alias (free)

typedef _Float16 f16x8 __attribute__((ext_vector_type(8)));
typedef _Float16 f16x4 __attribute__((ext_vector_type(4)));
typedef float    f32x4 __attribute__((ext_vector_type(4)));

// ---------------------------------------------------------------------------
// Precompute (68 blocks, ~5 us):
//   blocks 0..63 : (l = b>>4, row-group ng = b&15) -> Mt[l][16ng..16ng+16)[*]
//   blocks 64..67: W1t[n][k] = W1[k][n] transpose.
// ---------------------------------------------------------------------------
__global__ void fno_precompute(const float* __restrict__ W1,
                               const float* __restrict__ fw,
                               const float* __restrict__ lw,
                               _Float16* __restrict__ Mt,    // [4][256][KAUG]
                               _Float16* __restrict__ W1t)   // [256][64]
{
    const int t = threadIdx.x;          // 0..255
    const int b = blockIdx.x;
    if (b < 64) {
        const int l  = b >> 4;
        const int ng = b & 15;
        __shared__ float cosTab[256];
        __shared__ float cs[256];
        cosTab[t] = cosf((float)t * (6.28318530717958647692f / 256.0f));
        __syncthreads();
        // cs[t] = irfft(fw_l)[t]
        {
            const float* fwl = fw + l * 129;
            float s = fwl[0];
            #pragma unroll 4
            for (int k = 1; k < 128; ++k)
                s += 2.0f * fwl[k] * cosTab[(k * t) & 255];
            s += fwl[128] * ((t & 1) ? -1.0f : 1.0f);
            cs[t] = s * (1.0f / 256.0f);
        }
        __syncthreads();
        for (int idx = t; idx < 16 * KAUG; idx += 256) {
            const int n = ng * 16 + idx / KAUG;
            const int k = idx % KAUG;
            float v = 0.0f;
            if (k < 253)               v = cs[(n - k - 3) & 255];  // conv: h[k] -> d[k+3]
            if (k == n)                v += lw[l * 256 + n];       // diagonal residual lw
            if (k >= 256 && k < 259)   v = cs[(n - (k - 256)) & 255]; // x rows
            Mt[((size_t)l * 256 + n) * KAUG + k] = (_Float16)v;
        }
    } else {
        const int base = (b - 64) * 4096;
        #pragma unroll
        for (int i = 0; i < 16; ++i) {
            const int idx = base + t + i * 256;
            const int n = idx >> 6, k = idx & 63;
            W1t[idx] = (_Float16)W1[k * 256 + n];
        }
    }
}

// ---------------------------------------------------------------------------
// Fused main kernel. Block = 64 rows x 256 threads (4 waves); wave w owns
// feature columns [64w, 64w+64).
// __launch_bounds__(256,3): 3 waves/EU -> 3 blocks/CU, 170-reg unified budget.
// (256,4) spilled ~32B/thread (WRITE_SIZE 1MB->31.6MB, MfmaUtil 44->34):
// acc=64 AGPR + mfrag/hfrag/addr did not fit 128 regs. 170 regs -> no spill,
// 12 waves/CU (was 8 at BM=128) for latency hiding.
// x-augmentation lives in hA cols 256..258 (LDA pad); the ks=8 K-chunk reads
// cols 256..287: cols 259..263 are zeros, cols 264..287 over-read into the
// next row's h values -- finite, and multiplied by exactly-zero Mt weights.
// Pad row BM is zeroed so the last row's over-read never sees uninit LDS.
// MFMA operand order is (Mt_frag, h_frag) so D = h^T-layout: lane holds
// row = lane&15, features 4q..4q+3 -> vectorized f16x4 epilogue writes.
// ---------------------------------------------------------------------------
__global__ __launch_bounds__(256, 3)
void fno_main(const float* __restrict__ mu,
              const float* __restrict__ x,
              const float* __restrict__ b1,
              const float* __restrict__ W2,
              const float* __restrict__ b2,
              const _Float16* __restrict__ Mt,
              const _Float16* __restrict__ W1t,
              float* __restrict__ out)
{
    __shared__ __align__(16) _Float16 hA[(BM + 1) * LDA];  // h state + x cols + pad row
    __shared__ float b1s[256];
    __shared__ float W2s[256];
    __shared__ float red[256];

    const int t    = threadIdx.x;
    const int w    = t >> 6;        // wave id: feature stripe 64*w
    const int lane = t & 63;
    const int i16  = lane & 15;     // Mt-frag feature / h-frag row / D row
    const int q    = lane >> 4;     // quad: k-chunk (inputs), feature group (D)
    const int r0   = blockIdx.x * BM;

    // ---- stage mu -> hA cols 0..63 (fp16); x -> cols 256..263; zero pad row ----
    {
        const float4* mu4 = (const float4*)mu + (size_t)r0 * 16;  // 16 float4 per row
        #pragma unroll
        for (int j = 0; j < 4; ++j) {
            int f = t + 256 * j;
            int row = f >> 4, c4 = f & 15;
            float4 v = mu4[f];
            f16x4 h;
            h[0] = (_Float16)v.x; h[1] = (_Float16)v.y;
            h[2] = (_Float16)v.z; h[3] = (_Float16)v.w;
            *(f16x4*)&hA[row * LDA + c4 * 4] = h;
        }
        if (t < BM) {
            const float* xp = x + (size_t)(r0 + t) * 3;
            f16x8 hx = {(_Float16)xp[0], (_Float16)xp[1], (_Float16)xp[2],
                        (_Float16)0, (_Float16)0, (_Float16)0,
                        (_Float16)0, (_Float16)0};
            *(f16x8*)&hA[t * LDA + 256] = hx;
        }
        if (t < 33) {              // 33 * 8 = 264 halves: the whole pad row
            f16x8 z8 = {};
            *(f16x8*)&hA[BM * LDA + 8 * t] = z8;
        }
        b1s[t] = b1[t];
        W2s[t] = W2[t];
    }
    __syncthreads();

    const f32x4 fz = {0.f, 0.f, 0.f, 0.f};
    f32x4 acc[4][4];   // [feature-tile][row-tile], 64 regs

    // ================= encoder: h = relu(mu @ W1 + b1), K = 64 =================
    #pragma unroll
    for (int ft = 0; ft < 4; ++ft)
        #pragma unroll
        for (int rt = 0; rt < 4; ++rt) acc[ft][rt] = fz;

    #pragma unroll
    for (int ks = 0; ks < 2; ++ks) {
        const int kb = ks * 32;
        f16x8 mfrag[4];
        #pragma unroll
        for (int ft = 0; ft < 4; ++ft) {
            int n = 64 * w + 16 * ft + i16;
            mfrag[ft] = *(const f16x8*)(W1t + n * 64 + kb + 8 * q);
        }
        #pragma unroll
        for (int rt = 0; rt < 4; ++rt) {
            f16x8 hfrag = *(const f16x8*)&hA[(16 * rt + i16) * LDA + kb + 8 * q];
            #pragma unroll
            for (int ft = 0; ft < 4; ++ft)
                acc[ft][rt] = __builtin_amdgcn_mfma_f32_16x16x32_f16(
                    mfrag[ft], hfrag, acc[ft][rt], 0, 0, 0);
        }
    }
    __syncthreads();   // all reads of mu-region done before overwrite
    #pragma unroll
    for (int ft = 0; ft < 4; ++ft) {
        const int f = 64 * w + 16 * ft + 4 * q;
        const float4 bias = *(const float4*)&b1s[f];
        #pragma unroll
        for (int rt = 0; rt < 4; ++rt) {
            const int row = 16 * rt + i16;
            f32x4 v = acc[ft][rt];
            f16x4 hv;
            hv[0] = (_Float16)fmaxf(v[0] + bias.x, 0.f);
            hv[1] = (_Float16)fmaxf(v[1] + bias.y, 0.f);
            hv[2] = (_Float16)fmaxf(v[2] + bias.z, 0.f);
            hv[3] = (_Float16)fmaxf(v[3] + bias.w, 0.f);
            *(f16x4*)&hA[row * LDA + f] = hv;
        }
    }

    // ================= 4 Fourier layers: h = relu([h|x] @ M_l) ================
    #pragma unroll 1
    for (int l = 0; l < 4; ++l) {
        __syncthreads();   // hA writes from previous stage visible
        #pragma unroll
        for (int ft = 0; ft < 4; ++ft)
            #pragma unroll
            for (int rt = 0; rt < 4; ++rt) acc[ft][rt] = fz;

        const _Float16* Ml = Mt + (size_t)l * 256 * KAUG;
        #pragma unroll
        for (int ks = 0; ks < 9; ++ks) {
            const int kb = ks * 32;
            f16x8 mfrag[4];
            #pragma unroll
            for (int ft = 0; ft < 4; ++ft) {
                int n = 64 * w + 16 * ft + i16;
                mfrag[ft] = *(const f16x8*)(Ml + n * KAUG + kb + 8 * q);
            }
            #pragma unroll
            for (int rt = 0; rt < 4; ++rt) {
                // ks==8 reads cols 256..287: x cols + zeros + next-row overlap (zero weights)
                f16x8 hfrag = *(const f16x8*)&hA[(16 * rt + i16) * LDA + kb + 8 * q];
                #pragma unroll
                for (int ft = 0; ft < 4; ++ft)
                    acc[ft][rt] = __builtin_amdgcn_mfma_f32_16x16x32_f16(
                        mfrag[ft], hfrag, acc[ft][rt], 0, 0, 0);
            }
        }
        __syncthreads();   // all hA reads done before overwrite
        #pragma unroll
        for (int ft = 0; ft < 4; ++ft) {
            const int f = 64 * w + 16 * ft + 4 * q;
            #pragma unroll
            for (int rt = 0; rt < 4; ++rt) {
                const int row = 16 * rt + i16;
                f32x4 v = acc[ft][rt];
                f16x4 hv;
                hv[0] = (_Float16)fmaxf(v[0], 0.f);
                hv[1] = (_Float16)fmaxf(v[1], 0.f);
                hv[2] = (_Float16)fmaxf(v[2], 0.f);
                hv[3] = (_Float16)fmaxf(v[3], 0.f);
                *(f16x4*)&hA[row * LDA + f] = hv;
            }
        }
    }

    // ================= decoder: out = h @ W2 + b2 =============================
    __syncthreads();
    {
        const int r  = t & 63;          // row (lane)
        const int n0 = w * 64;          // wave w covers cols 64w..64w+63
        float s = 0.f;
        #pragma unroll
        for (int j = 0; j < 8; ++j) {
            f16x8 v = *(const f16x8*)&hA[r * LDA + n0 + 8 * j];
            const float* wp = &W2s[n0 + 8 * j];
            s += (float)v[0] * wp[0] + (float)v[1] * wp[1]
               + (float)v[2] * wp[2] + (float)v[3] * wp[3]
               + (float)v[4] * wp[4] + (float)v[5] * wp[5]
               + (float)v[6] * wp[6] + (float)v[7] * wp[7];
        }
        red[t] = s;
        __syncthreads();
        if (t < 64)
            out[r0 + t] = red[t] + red[64 + t] + red[128 + t] + red[192 + t] + b2[0];
    }
}

// ---------------------------------------------------------------------------
extern "C" void kernel_launch(void* const* d_in, const int* in_sizes, int n_in,
                              void* d_out, int out_size, void* d_ws, size_t ws_size,
                              hipStream_t stream) {
    const float* mu = (const float*)d_in[0];
    const float* x  = (const float*)d_in[1];
    const float* W1 = (const float*)d_in[2];
    const float* b1 = (const float*)d_in[3];
    const float* fw = (const float*)d_in[4];
    const float* lw = (const float*)d_in[5];
    const float* W2 = (const float*)d_in[6];
    const float* b2 = (const float*)d_in[7];
    float* out = (float*)d_out;

    _Float16* Mt  = (_Float16*)d_ws;
    _Float16* W1t = Mt + 4 * 256 * KAUG;

    fno_precompute<<<68, 256, 0, stream>>>(W1, fw, lw, Mt, W1t);
    fno_main<<<N_B / BM, 256, 0, stream>>>(mu, x, b1, W2, b2, Mt, W1t, out);
}

// Round 4
// 248.627 us; speedup vs baseline: 1.1657x; 1.1433x over previous
//
#include <hip/hip_runtime.h>

#define N_B   262144
#define BM    128      // proven best tile: 32 MFMA per mfrag group, barriers amortized
#define KAUG  288      // 256 (h) + 32 (x-augmentation, only 3 used)
#define LDA   264      // hA row stride in halves: 528B; 132 dw = 4 mod 32 -> 2-way bank alias (free)

typedef _Float16 f16x8 __attribute__((ext_vector_type(8)));
typedef _Float16 f16x4 __attribute__((ext_vector_type(4)));
typedef float    f32x4 __attribute__((ext_vector_type(4)));

// ---------------------------------------------------------------------------
// Precompute (68 blocks, ~5 us):
//   blocks 0..63 : (l = b>>4, row-group ng = b&15) -> Mt[l][16ng..16ng+16)[*]
//   blocks 64..67: W1t[n][k] = W1[k][n] transpose.
// ---------------------------------------------------------------------------
__global__ void fno_precompute(const float* __restrict__ W1,
                               const float* __restrict__ fw,
                               const float* __restrict__ lw,
                               _Float16* __restrict__ Mt,    // [4][256][KAUG]
                               _Float16* __restrict__ W1t)   // [256][64]
{
    const int t = threadIdx.x;          // 0..255
    const int b = blockIdx.x;
    if (b < 64) {
        const int l  = b >> 4;
        const int ng = b & 15;
        __shared__ float cosTab[256];
        __shared__ float cs[256];
        cosTab[t] = cosf((float)t * (6.28318530717958647692f / 256.0f));
        __syncthreads();
        // cs[t] = irfft(fw_l)[t]
        {
            const float* fwl = fw + l * 129;
            float s = fwl[0];
            #pragma unroll 4
            for (int k = 1; k < 128; ++k)
                s += 2.0f * fwl[k] * cosTab[(k * t) & 255];
            s += fwl[128] * ((t & 1) ? -1.0f : 1.0f);
            cs[t] = s * (1.0f / 256.0f);
        }
        __syncthreads();
        for (int idx = t; idx < 16 * KAUG; idx += 256) {
            const int n = ng * 16 + idx / KAUG;
            const int k = idx % KAUG;
            float v = 0.0f;
            if (k < 253)               v = cs[(n - k - 3) & 255];  // conv: h[k] -> d[k+3]
            if (k == n)                v += lw[l * 256 + n];       // diagonal residual lw
            if (k >= 256 && k < 259)   v = cs[(n - (k - 256)) & 255]; // x rows
            Mt[((size_t)l * 256 + n) * KAUG + k] = (_Float16)v;
        }
    } else {
        const int base = (b - 64) * 4096;
        #pragma unroll
        for (int i = 0; i < 16; ++i) {
            const int idx = base + t + i * 256;
            const int n = idx >> 6, k = idx & 63;
            W1t[idx] = (_Float16)W1[k * 256 + n];
        }
    }
}

// ---------------------------------------------------------------------------
// Fused main kernel. Block = 128 rows x 256 threads (4 waves); wave w owns
// feature columns [64w, 64w+64). 2 blocks/CU (LDS 70.7 KB).
// NEW vs 162us baseline: mfrag global(L2) loads are software-pipelined with an
// explicit 2-buffer rotate -- the 4 loads for K-chunk ks+1 are issued before
// the 32 MFMAs of chunk ks, so the ~250cyc L2 latency hides under MFMA issue.
// (BM=64 experiments showed the per-chunk L2 wait, not occupancy, is the
// exposed term: MfmaUtil 44 with nothing in flight across chunk boundaries.)
// x-augmentation lives in hA cols 256..258 (pad): ks=8 reads cols 256..287 =
// x + zeros + next-row over-read hitting exactly-zero Mt weights; pad row BM
// is zeroed so row 127's over-read never sees uninit LDS.
// MFMA operand order is (Mt_frag, h_frag) so D = h^T-layout: lane holds
// row = lane&15, features 4q..4q+3 -> vectorized f16x4 epilogue writes.
// Register budget: acc 128 + mfrag dbuf 32 + addressing ~= 240 < 256
// (__launch_bounds__(256,2)); watch WRITE_SIZE for spill (must stay ~1MB).
// ---------------------------------------------------------------------------

#define LOADM(DST, BASE, FSTR, KB)                                        \
    { _Pragma("unroll")                                                   \
      for (int ft = 0; ft < 4; ++ft)                                      \
          DST[ft] = *(const f16x8*)((BASE) + (FSTR) * ft + (KB)); }

#define KSTEP(CUR, KB)                                                    \
    { _Pragma("unroll")                                                   \
      for (int rt = 0; rt < 8; ++rt) {                                    \
          f16x8 hfrag = *(const f16x8*)&hA[hoff + 16 * rt * LDA + (KB)];  \
          _Pragma("unroll")                                               \
          for (int ft = 0; ft < 4; ++ft)                                  \
              acc[ft][rt] = __builtin_amdgcn_mfma_f32_16x16x32_f16(       \
                  CUR[ft], hfrag, acc[ft][rt], 0, 0, 0);                  \
      } }

__global__ __launch_bounds__(256, 2)
void fno_main(const float* __restrict__ mu,
              const float* __restrict__ x,
              const float* __restrict__ b1,
              const float* __restrict__ W2,
              const float* __restrict__ b2,
              const _Float16* __restrict__ Mt,
              const _Float16* __restrict__ W1t,
              float* __restrict__ out)
{
    __shared__ __align__(16) _Float16 hA[(BM + 1) * LDA];  // h state + x cols + pad row
    __shared__ float b1s[256];
    __shared__ float W2s[256];
    __shared__ float red[BM];

    const int t    = threadIdx.x;
    const int w    = t >> 6;        // wave id: feature stripe 64*w
    const int lane = t & 63;
    const int i16  = lane & 15;     // Mt-frag feature / h-frag row / D row
    const int q    = lane >> 4;     // quad: k-chunk (inputs), feature group (D)
    const int r0   = blockIdx.x * BM;
    const int hoff = i16 * LDA + 8 * q;   // hfrag base offset (halves)

    // ---- stage mu -> hA cols 0..63 (fp16); x -> cols 256..263; zero pad row ----
    {
        const float4* mu4 = (const float4*)mu + (size_t)r0 * 16;  // 16 float4 per row
        #pragma unroll
        for (int j = 0; j < 8; ++j) {
            int f = t + 256 * j;
            int row = f >> 4, c4 = f & 15;
            float4 v = mu4[f];
            f16x4 h;
            h[0] = (_Float16)v.x; h[1] = (_Float16)v.y;
            h[2] = (_Float16)v.z; h[3] = (_Float16)v.w;
            *(f16x4*)&hA[row * LDA + c4 * 4] = h;
        }
        if (t < BM) {
            const float* xp = x + (size_t)(r0 + t) * 3;
            f16x8 hx = {(_Float16)xp[0], (_Float16)xp[1], (_Float16)xp[2],
                        (_Float16)0, (_Float16)0, (_Float16)0,
                        (_Float16)0, (_Float16)0};
            *(f16x8*)&hA[t * LDA + 256] = hx;
        }
        if (t < 33) {              // 33 * 8 = 264 halves: the whole pad row
            f16x8 z8 = {};
            *(f16x8*)&hA[BM * LDA + 8 * t] = z8;
        }
        b1s[t] = b1[t];
        W2s[t] = W2[t];
    }
    __syncthreads();

    const f32x4 fz = {0.f, 0.f, 0.f, 0.f};
    f32x4 acc[4][8];   // [feature-tile][row-tile], 128 regs

    // ================= encoder: h = relu(mu @ W1 + b1), K = 64 =================
    #pragma unroll
    for (int ft = 0; ft < 4; ++ft)
        #pragma unroll
        for (int rt = 0; rt < 8; ++rt) acc[ft][rt] = fz;

    {
        const _Float16* W1p = W1t + (64 * w + i16) * 64 + 8 * q;
        f16x8 m0[4], m1[4];
        LOADM(m0, W1p, 16 * 64, 0)
        LOADM(m1, W1p, 16 * 64, 32)
        KSTEP(m0, 0)
        KSTEP(m1, 32)
    }
    __syncthreads();   // all reads of mu-region done before overwrite
    #pragma unroll
    for (int ft = 0; ft < 4; ++ft) {
        const int f = 64 * w + 16 * ft + 4 * q;
        const float4 bias = *(const float4*)&b1s[f];
        #pragma unroll
        for (int rt = 0; rt < 8; ++rt) {
            const int row = 16 * rt + i16;
            f32x4 v = acc[ft][rt];
            f16x4 hv;
            hv[0] = (_Float16)fmaxf(v[0] + bias.x, 0.f);
            hv[1] = (_Float16)fmaxf(v[1] + bias.y, 0.f);
            hv[2] = (_Float16)fmaxf(v[2] + bias.z, 0.f);
            hv[3] = (_Float16)fmaxf(v[3] + bias.w, 0.f);
            *(f16x4*)&hA[row * LDA + f] = hv;
        }
    }

    // ================= 4 Fourier layers: h = relu([h|x] @ M_l) ================
    #pragma unroll 1
    for (int l = 0; l < 4; ++l) {
        __syncthreads();   // hA writes from previous stage visible
        #pragma unroll
        for (int ft = 0; ft < 4; ++ft)
            #pragma unroll
            for (int rt = 0; rt < 8; ++rt) acc[ft][rt] = fz;

        const _Float16* Mlp = Mt + (size_t)l * 256 * KAUG
                                 + (64 * w + i16) * KAUG + 8 * q;
        f16x8 m0[4], m1[4];
        // 2-deep rotate: loads for chunk ks+1 issue before chunk ks's MFMAs wait
        LOADM(m0, Mlp, 16 * KAUG, 0)
        LOADM(m1, Mlp, 16 * KAUG, 32)
        KSTEP(m0, 0)    LOADM(m0, Mlp, 16 * KAUG, 64)
        KSTEP(m1, 32)   LOADM(m1, Mlp, 16 * KAUG, 96)
        KSTEP(m0, 64)   LOADM(m0, Mlp, 16 * KAUG, 128)
        KSTEP(m1, 96)   LOADM(m1, Mlp, 16 * KAUG, 160)
        KSTEP(m0, 128)  LOADM(m0, Mlp, 16 * KAUG, 192)
        KSTEP(m1, 160)  LOADM(m1, Mlp, 16 * KAUG, 224)
        KSTEP(m0, 192)  LOADM(m0, Mlp, 16 * KAUG, 256)
        KSTEP(m1, 224)
        KSTEP(m0, 256)   // ks=8: x cols + zeros + next-row over-read (zero weights)

        __syncthreads();   // all hA reads done before overwrite
        #pragma unroll
        for (int ft = 0; ft < 4; ++ft) {
            const int f = 64 * w + 16 * ft + 4 * q;
            #pragma unroll
            for (int rt = 0; rt < 8; ++rt) {
                const int row = 16 * rt + i16;
                f32x4 v = acc[ft][rt];
                f16x4 hv;
                hv[0] = (_Float16)fmaxf(v[0], 0.f);
                hv[1] = (_Float16)fmaxf(v[1], 0.f);
                hv[2] = (_Float16)fmaxf(v[2], 0.f);
                hv[3] = (_Float16)fmaxf(v[3], 0.f);
                *(f16x4*)&hA[row * LDA + f] = hv;
            }
        }
    }

    // ================= decoder: out = h @ W2 + b2 =============================
    __syncthreads();
    {
        const int r  = t & 127;
        const int hf = t >> 7;        // two threads per row, half the columns each
        const int n0 = hf * 128;
        float s = 0.f;
        #pragma unroll
        for (int j = 0; j < 16; ++j) {
            f16x8 v = *(const f16x8*)&hA[r * LDA + n0 + 8 * j];
            const float* wp = &W2s[n0 + 8 * j];
            s += (float)v[0] * wp[0] + (float)v[1] * wp[1]
               + (float)v[2] * wp[2] + (float)v[3] * wp[3]
               + (float)v[4] * wp[4] + (float)v[5] * wp[5]
               + (float)v[6] * wp[6] + (float)v[7] * wp[7];
        }
        if (hf) red[r] = s;
        __syncthreads();
        if (!hf) out[r0 + r] = s + red[r] + b2[0];
    }
}

// ---------------------------------------------------------------------------
extern "C" void kernel_launch(void* const* d_in, const int* in_sizes, int n_in,
                              void* d_out, int out_size, void* d_ws, size_t ws_size,
                              hipStream_t stream) {
    const float* mu = (const float*)d_in[0];
    const float* x  = (const float*)d_in[1];
    const float* W1 = (const float*)d_in[2];
    const float* b1 = (const float*)d_in[3];
    const float* fw = (const float*)d_in[4];
    const float* lw = (const float*)d_in[5];
    const float* W2 = (const float*)d_in[6];
    const float* b2 = (const float*)d_in[7];
    float* out = (float*)d_out;

    _Float16* Mt  = (_Float16*)d_ws;
    _Float16* W1t = Mt + 4 * 256 * KAUG;

    fno_precompute<<<68, 256, 0, stream>>>(W1, fw, lw, Mt, W1t);
    fno_main<<<N_B / BM, 256, 0, stream>>>(mu, x, b1, W2, b2, Mt, W1t, out);
}